// Round 17
// baseline (767.832 us; speedup 1.0000x reference)
//
#include <hip/hip_runtime.h>

#define H_DIM 128
#define F_IN  384

typedef __bf16 v8bf __attribute__((ext_vector_type(8)));
typedef float  v4f  __attribute__((ext_vector_type(4)));

// order-preserving float <-> uint encoding for atomicMax
__device__ __forceinline__ unsigned enc_f32(float v) {
    unsigned u = __float_as_uint(v);
    return (u & 0x80000000u) ? ~u : (u | 0x80000000u);
}
__device__ __forceinline__ float dec_f32(unsigned e) {
    if (e == 0u) return 0.0f;  // untouched node -> 0 (matches reference where())
    unsigned u = (e & 0x80000000u) ? (e & 0x7fffffffu) : ~e;
    return __uint_as_float(u);
}

// W1 [F_IN][H] fp32 -> W1T [H][F_IN] bf16 ; W2 [H][H] fp32 -> W2T [H][H] bf16
__global__ __launch_bounds__(256) void wconvert(const float* __restrict__ W1,
                                                const float* __restrict__ W2,
                                                __bf16* __restrict__ W1T,
                                                __bf16* __restrict__ W2T) {
    int i = blockIdx.x * 256 + threadIdx.x;
    if (i < F_IN * H_DIM) {
        int col = i / F_IN, k = i % F_IN;
        W1T[i] = (__bf16)W1[k * H_DIM + col];
    } else if (i < F_IN * H_DIM + H_DIM * H_DIM) {
        int j = i - F_IN * H_DIM;
        int col = j / H_DIM, k = j % H_DIM;
        W2T[j] = (__bf16)W2[k * H_DIM + col];
    }
}

// 128 edges per block, 256 threads (4 waves), B-reuse x2 (r16 core).
// LDS footprint cut to EXACTLY 32KB -> 5 blocks/CU = 20 waves/CU:
//  - hs is [128][128] bf16 with a 16B-chunk XOR swizzle (chunk ^= row&7),
//    overlaying wb (20.5KB) after the K-loop
//  - idx/bias LDS arrays eliminated (biases in regs via L1-broadcast loads;
//    node ids loaded directly in the epilogue)
// __launch_bounds__(256,5) caps VGPR at 102 for 5 waves/SIMD.
__global__ __launch_bounds__(256, 5) void mlp_scatter(
    const float* __restrict__ leaf, const int* __restrict__ nidx,
    const __bf16* __restrict__ W1T, const __bf16* __restrict__ W2T,
    const float* __restrict__ b1, const float* __restrict__ b2,
    unsigned* __restrict__ agg, int E)
{
    __shared__ char smem[32768] __attribute__((aligned(16)));
    __bf16 (*wb)[128][40] = (__bf16 (*)[128][40])smem;   // dies at K-loop end
    __bf16* hsp           = (__bf16*)smem;               // swizzled [128][128], lives after

    const int t  = threadIdx.x;
    const int w  = t >> 6;
    const int l  = t & 63;
    const int lr = l & 15;   // row/col within fragment
    const int lg = l >> 4;   // k-group
    const long e0 = (long)blockIdx.x * 128;

    // per-lane layer-1 biases in registers (L1 broadcast)
    float bb1[8];
#pragma unroll
    for (int f = 0; f < 8; ++f) bb1[f] = b1[f * 16 + lr];

    // stage W1T chunk ks=0 into buffer 0 (each thread: 32B of one column)
    {
        const int col = t >> 1, kh = (t & 1) * 16;
        const v8bf* src = (const v8bf*)(W1T + col * F_IN + kh);
        *(v8bf*)&wb[0][col][kh]     = src[0];
        *(v8bf*)&wb[0][col][kh + 8] = src[1];
    }

    long erA = e0 + w * 32 + lr;        // group A rows
    long erB = e0 + w * 32 + 16 + lr;   // group B rows
    if (erA >= E) erA = E - 1;          // clamp (tail-safe)
    if (erB >= E) erB = E - 1;
    const float* arowA = leaf + erA * (long)F_IN + lg * 8;
    const float* arowB = leaf + erB * (long)F_IN + lg * 8;

    const v4f vzero = {0.f, 0.f, 0.f, 0.f};
    v4f accA[8], accB[8];
#pragma unroll
    for (int f = 0; f < 8; ++f) { accA[f] = vzero; accB[f] = vzero; }

    float4 aA0 = *(const float4*)(arowA);
    float4 aA1 = *(const float4*)(arowA + 4);
    float4 aB0 = *(const float4*)(arowB);
    float4 aB1 = *(const float4*)(arowB + 4);
    __syncthreads();   // wb[0] visible

    // ---- layer 1: h = x @ W1, K=384 in 12 steps of 32 ----
    for (int ks = 0; ks < 12; ++ks) {
        float4 nA0 = aA0, nA1 = aA1, nB0 = aB0, nB1 = aB1;
        if (ks + 1 < 12) {
            nA0 = *(const float4*)(arowA + (ks + 1) * 32);
            nA1 = *(const float4*)(arowA + (ks + 1) * 32 + 4);
            nB0 = *(const float4*)(arowB + (ks + 1) * 32);
            nB1 = *(const float4*)(arowB + (ks + 1) * 32 + 4);
            const int col = t >> 1, kh = (t & 1) * 16;
            const v8bf* src = (const v8bf*)(W1T + col * F_IN + (ks + 1) * 32 + kh);
            const int b = (ks + 1) & 1;
            *(v8bf*)&wb[b][col][kh]     = src[0];
            *(v8bf*)&wb[b][col][kh + 8] = src[1];
        }
        v8bf afA, afB;
        afA[0] = (__bf16)aA0.x; afA[1] = (__bf16)aA0.y; afA[2] = (__bf16)aA0.z; afA[3] = (__bf16)aA0.w;
        afA[4] = (__bf16)aA1.x; afA[5] = (__bf16)aA1.y; afA[6] = (__bf16)aA1.z; afA[7] = (__bf16)aA1.w;
        afB[0] = (__bf16)aB0.x; afB[1] = (__bf16)aB0.y; afB[2] = (__bf16)aB0.z; afB[3] = (__bf16)aB0.w;
        afB[4] = (__bf16)aB1.x; afB[5] = (__bf16)aB1.y; afB[6] = (__bf16)aB1.z; afB[7] = (__bf16)aB1.w;
        const int cb = ks & 1;
#pragma unroll
        for (int f = 0; f < 8; ++f) {
            v8bf bfv = *(const v8bf*)&wb[cb][f * 16 + lr][lg * 8];
            accA[f] = __builtin_amdgcn_mfma_f32_16x16x32_bf16(afA, bfv, accA[f], 0, 0, 0);
            accB[f] = __builtin_amdgcn_mfma_f32_16x16x32_bf16(afB, bfv, accB[f], 0, 0, 0);
        }
        aA0 = nA0; aA1 = nA1; aB0 = nB0; aB1 = nB1;
        __syncthreads();
    }
    // loop's final barrier: all wb reads complete -> hs may overlay wb

    // ---- relu + bias -> swizzled hs (wave-private rows; no barrier) ----
    // addr(row, col) = row*128 + ((col>>3) ^ (row&7))*8 + (col&7)
#pragma unroll
    for (int f = 0; f < 8; ++f) {
#pragma unroll
        for (int j = 0; j < 4; ++j) {
            const int rA = w * 32 + lg * 4 + j;
            const int rB = rA + 16;
            const int cA = f * 16 + lr;
            float vA = fmaxf(accA[f][j] + bb1[f], 0.0f);
            float vB = fmaxf(accB[f][j] + bb1[f], 0.0f);
            hsp[rA * 128 + (((cA >> 3) ^ (rA & 7)) << 3) + (cA & 7)] = (__bf16)vA;
            hsp[rB * 128 + (((cA >> 3) ^ (rB & 7)) << 3) + (cA & 7)] = (__bf16)vB;
        }
    }

    // ---- layer 2: m = h @ W2, K=128 in 4 steps; W2T frags from L1/L2, reused x2 ----
    v4f acc2A[8], acc2B[8];
#pragma unroll
    for (int f = 0; f < 8; ++f) { acc2A[f] = vzero; acc2B[f] = vzero; }
#pragma unroll
    for (int ks = 0; ks < 4; ++ks) {
        const int rA = w * 32 + lr, rB = rA + 16;
        v8bf afA2 = *(const v8bf*)&hsp[rA * 128 + (((ks * 4 + lg) ^ (rA & 7)) << 3)];
        v8bf afB2 = *(const v8bf*)&hsp[rB * 128 + (((ks * 4 + lg) ^ (rB & 7)) << 3)];
#pragma unroll
        for (int f = 0; f < 8; ++f) {
            v8bf bfv = *(const v8bf*)(W2T + (f * 16 + lr) * H_DIM + ks * 32 + lg * 8);
            acc2A[f] = __builtin_amdgcn_mfma_f32_16x16x32_bf16(afA2, bfv, acc2A[f], 0, 0, 0);
            acc2B[f] = __builtin_amdgcn_mfma_f32_16x16x32_bf16(afB2, bfv, acc2B[f], 0, 0, 0);
        }
    }

    // ---- epilogue: + b2 (regs), node-ids direct from global, scatter-max ----
    float bb2[8];
#pragma unroll
    for (int f = 0; f < 8; ++f) bb2[f] = b2[f * 16 + lr];
#pragma unroll
    for (int g = 0; g < 2; ++g) {
        const int rb = w * 32 + g * 16 + lg * 4;
#pragma unroll
        for (int j = 0; j < 4; ++j) {
            const long ej = e0 + rb + j;
            if (ej < E) {
                const int node = nidx[ej];           // L1-resident (512B/block)
                unsigned* dst = agg + (long)node * H_DIM + lr;
#pragma unroll
                for (int f = 0; f < 8; ++f) {
                    float v = (g ? acc2B[f][j] : acc2A[f][j]) + bb2[f];
                    atomicMax(dst + f * 16, enc_f32(v));
                }
            }
        }
    }
}

// one wave per node row: lang = center + dec(agg); out = cos(gcn, lang)
__global__ __launch_bounds__(256) void cos_kernel(
    const float* __restrict__ center, const float* __restrict__ gcn,
    const unsigned* __restrict__ agg, float* __restrict__ out, int N)
{
    const int w = threadIdx.x >> 6, l = threadIdx.x & 63;
    const long row = (long)blockIdx.x * 4 + w;
    if (row >= N) return;
    const float2 g2 = *(const float2*)(gcn    + row * H_DIM + l * 2);
    const float2 c2 = *(const float2*)(center + row * H_DIM + l * 2);
    const uint2  e2 = *(const uint2*) (agg    + row * H_DIM + l * 2);
    const float l0 = c2.x + dec_f32(e2.x);
    const float l1 = c2.y + dec_f32(e2.y);
    float sgl = g2.x * l0 + g2.y * l1;
    float sgg = g2.x * g2.x + g2.y * g2.y;
    float sll = l0 * l0 + l1 * l1;
#pragma unroll
    for (int off = 32; off; off >>= 1) {
        sgl += __shfl_xor(sgl, off);
        sgg += __shfl_xor(sgg, off);
        sll += __shfl_xor(sll, off);
    }
    if (l == 0) {
        const float na = fmaxf(sqrtf(sgg), 1e-8f);
        const float nb = fmaxf(sqrtf(sll), 1e-8f);
        out[row] = sgl / (na * nb);
    }
}

extern "C" void kernel_launch(void* const* d_in, const int* in_sizes, int n_in,
                              void* d_out, int out_size, void* d_ws, size_t ws_size,
                              hipStream_t stream) {
    const float* center = (const float*)d_in[0];
    const float* leaf   = (const float*)d_in[1];
    const int*   nidx   = (const int*)  d_in[2];
    const float* gcn    = (const float*)d_in[3];
    const float* W1     = (const float*)d_in[4];
    const float* b1     = (const float*)d_in[5];
    const float* W2     = (const float*)d_in[6];
    const float* b2     = (const float*)d_in[7];

    const int E = in_sizes[2];             // 1,000,000
    const int N = in_sizes[0] / H_DIM;     // 65,536

    unsigned* agg = (unsigned*)d_ws;
    const size_t aggBytes = (size_t)N * H_DIM * sizeof(unsigned);
    __bf16* W1T = (__bf16*)((char*)d_ws + aggBytes);
    __bf16* W2T = W1T + (size_t)F_IN * H_DIM;

    hipMemsetAsync(agg, 0, aggBytes, stream);
    wconvert<<<(F_IN * H_DIM + H_DIM * H_DIM + 255) / 256, 256, 0, stream>>>(W1, W2, W1T, W2T);
    mlp_scatter<<<(E + 127) / 128, 256, 0, stream>>>(leaf, nidx, W1T, W2T, b1, b2, agg, E);
    cos_kernel<<<(N + 3) / 4, 256, 0, stream>>>(center, gcn, agg, (float*)d_out, N);
}

// Round 18
// 606.166 us; speedup vs baseline: 1.2667x; 1.2667x over previous
//
#include <hip/hip_runtime.h>

#define H_DIM 128
#define F_IN  384

typedef __bf16 v8bf __attribute__((ext_vector_type(8)));
typedef float  v4f  __attribute__((ext_vector_type(4)));

// order-preserving float <-> uint encoding for atomicMax
__device__ __forceinline__ unsigned enc_f32(float v) {
    unsigned u = __float_as_uint(v);
    return (u & 0x80000000u) ? ~u : (u | 0x80000000u);
}
__device__ __forceinline__ float dec_f32(unsigned e) {
    if (e == 0u) return 0.0f;  // untouched node -> 0 (matches reference where())
    unsigned u = (e & 0x80000000u) ? (e & 0x7fffffffu) : ~e;
    return __uint_as_float(u);
}

// async 16B global->LDS DMA (dest = wave-uniform base + lane*16)
__device__ __forceinline__ void gload_lds16(const void* g, void* l) {
    __builtin_amdgcn_global_load_lds(
        (const __attribute__((address_space(1))) void*)g,
        (__attribute__((address_space(3))) void*)l, 16, 0, 0);
}

// W1 [F_IN][H] fp32 -> W1C chunk-major [12][128][32] bf16 with 16B-unit XOR
// pre-swizzle (c16 ^= row&3) so the linear DMA + swizzled read are conflict-
// spread (T2 both-sides involution). W2 [H][H] fp32 -> W2T [H][H] bf16.
__global__ __launch_bounds__(256) void wconvert(const float* __restrict__ W1,
                                                const float* __restrict__ W2,
                                                __bf16* __restrict__ W1C,
                                                __bf16* __restrict__ W2T) {
    int i = blockIdx.x * 256 + threadIdx.x;
    if (i < F_IN * H_DIM) {
        int chunk = i >> 12;            // 4096 elems per K=32 chunk
        int rem   = i & 4095;
        int row   = rem >> 5;           // output column 0..127
        int c16   = (rem >> 3) & 3;     // 16B unit within row
        int e     = rem & 7;
        int k     = chunk * 32 + (c16 ^ (row & 3)) * 8 + e;   // pre-swizzled source k
        W1C[i] = (__bf16)W1[k * H_DIM + row];
    } else if (i < F_IN * H_DIM + H_DIM * H_DIM) {
        int j = i - F_IN * H_DIM;
        int col = j / H_DIM, k = j % H_DIM;
        W2T[j] = (__bf16)W2[k * H_DIM + col];
    }
}

// 128 edges per block, 256 threads (4 waves), B-reuse x2 (r16 core, 596us).
// Single change vs r16: wb staging goes through global_load_lds DMA (no VGPR
// round-trip, no ds_write instructions) into a LINEAR [2][128][32] buffer;
// read-side bank spread via the wconvert pre-swizzle (read chunk lg^(lr&3)).
// hs[128][136] still overlays wb after the K-loop; ~36.4KB -> 4 blocks/CU.
__global__ __launch_bounds__(256, 4) void mlp_scatter(
    const float* __restrict__ leaf, const int* __restrict__ nidx,
    const __bf16* __restrict__ W1C, const __bf16* __restrict__ W2T,
    const float* __restrict__ b1, const float* __restrict__ b2,
    unsigned* __restrict__ agg, int E)
{
    // hs[128][136] bf16 = 34816 B; wb linear [2][128][32] = 16384 B overlays its head
    __shared__ char smem[34816] __attribute__((aligned(16)));
    __bf16* wbl       = (__bf16*)smem;               // [2][4096] elems, dies at K-loop end
    __bf16 (*hs)[136] = (__bf16 (*)[136])smem;       // lives after
    __shared__ int   idx_s[128];
    __shared__ float b1_s[H_DIM], b2_s[H_DIM];

    const int t  = threadIdx.x;
    const int w  = t >> 6;
    const int l  = t & 63;
    const int lr = l & 15;   // row/col within fragment
    const int lg = l >> 4;   // k-group
    const long e0 = (long)blockIdx.x * 128;

    if (t < 128) {
        long e = e0 + t;
        idx_s[t] = nidx[e < E ? e : (E - 1)];
    }
    if (t < H_DIM) { b1_s[t] = b1[t]; b2_s[t] = b2[t]; }

    // ---- stage W1 chunk 0 into buffer 0 via DMA (wave w: rows 32w..32w+31) ----
    {
        const char* gsrc = (const char*)W1C + w * 2048 + l * 16;
        char*       ldst = smem + w * 2048;
        gload_lds16(gsrc, ldst);
        gload_lds16(gsrc + 1024, ldst + 1024);
    }

    long erA = e0 + w * 32 + lr;        // group A rows
    long erB = e0 + w * 32 + 16 + lr;   // group B rows
    if (erA >= E) erA = E - 1;          // clamp (tail-safe)
    if (erB >= E) erB = E - 1;
    const float* arowA = leaf + erA * (long)F_IN + lg * 8;
    const float* arowB = leaf + erB * (long)F_IN + lg * 8;

    const v4f vzero = {0.f, 0.f, 0.f, 0.f};
    v4f accA[8], accB[8];
#pragma unroll
    for (int f = 0; f < 8; ++f) { accA[f] = vzero; accB[f] = vzero; }

    float4 aA0 = *(const float4*)(arowA);
    float4 aA1 = *(const float4*)(arowA + 4);
    float4 aB0 = *(const float4*)(arowB);
    float4 aB1 = *(const float4*)(arowB + 4);
    __syncthreads();   // drains DMA (vmcnt) + idx/bias ds_writes

    // ---- layer 1: h = x @ W1, K=384 in 12 steps of 32 ----
    for (int ks = 0; ks < 12; ++ks) {
        float4 nA0 = aA0, nA1 = aA1, nB0 = aB0, nB1 = aB1;
        if (ks + 1 < 12) {
            nA0 = *(const float4*)(arowA + (ks + 1) * 32);
            nA1 = *(const float4*)(arowA + (ks + 1) * 32 + 4);
            nB0 = *(const float4*)(arowB + (ks + 1) * 32);
            nB1 = *(const float4*)(arowB + (ks + 1) * 32 + 4);
            // DMA next chunk into the other buffer (no VGPR round-trip)
            const char* gsrc = (const char*)(W1C + (ks + 1) * 4096) + w * 2048 + l * 16;
            char*       ldst = smem + ((ks + 1) & 1) * 8192 + w * 2048;
            gload_lds16(gsrc, ldst);
            gload_lds16(gsrc + 1024, ldst + 1024);
        }
        v8bf afA, afB;
        afA[0] = (__bf16)aA0.x; afA[1] = (__bf16)aA0.y; afA[2] = (__bf16)aA0.z; afA[3] = (__bf16)aA0.w;
        afA[4] = (__bf16)aA1.x; afA[5] = (__bf16)aA1.y; afA[6] = (__bf16)aA1.z; afA[7] = (__bf16)aA1.w;
        afB[0] = (__bf16)aB0.x; afB[1] = (__bf16)aB0.y; afB[2] = (__bf16)aB0.z; afB[3] = (__bf16)aB0.w;
        afB[4] = (__bf16)aB1.x; afB[5] = (__bf16)aB1.y; afB[6] = (__bf16)aB1.z; afB[7] = (__bf16)aB1.w;
        const int cb = ks & 1;
        const int csw = (lg ^ (lr & 3)) << 3;   // swizzled 16B-unit offset (elems)
#pragma unroll
        for (int f = 0; f < 8; ++f) {
            v8bf bfv = *(const v8bf*)(wbl + cb * 4096 + (f * 16 + lr) * 32 + csw);
            accA[f] = __builtin_amdgcn_mfma_f32_16x16x32_bf16(afA, bfv, accA[f], 0, 0, 0);
            accB[f] = __builtin_amdgcn_mfma_f32_16x16x32_bf16(afB, bfv, accB[f], 0, 0, 0);
        }
        aA0 = nA0; aA1 = nA1; aB0 = nB0; aB1 = nB1;
        __syncthreads();
    }
    // loop's final barrier: all wb reads complete -> hs may overlay wb

    // ---- relu + bias -> bf16 hidden in LDS (wave-private rows) ----
#pragma unroll
    for (int f = 0; f < 8; ++f) {
        const float bb = b1_s[f * 16 + lr];
#pragma unroll
        for (int j = 0; j < 4; ++j) {
            float vA = fmaxf(accA[f][j] + bb, 0.0f);
            float vB = fmaxf(accB[f][j] + bb, 0.0f);
            hs[w * 32 + lg * 4 + j][f * 16 + lr]      = (__bf16)vA;
            hs[w * 32 + 16 + lg * 4 + j][f * 16 + lr] = (__bf16)vB;
        }
    }
    // no barrier: layer 2 reads only this wave's own rows (intra-wave lgkmcnt)

    // ---- layer 2: m = h @ W2, K=128 in 4 steps; W2T frags from L1/L2, reused x2 ----
    v4f acc2A[8], acc2B[8];
#pragma unroll
    for (int f = 0; f < 8; ++f) { acc2A[f] = vzero; acc2B[f] = vzero; }
#pragma unroll
    for (int ks = 0; ks < 4; ++ks) {
        v8bf afA2 = *(const v8bf*)&hs[w * 32 + lr][ks * 32 + lg * 8];
        v8bf afB2 = *(const v8bf*)&hs[w * 32 + 16 + lr][ks * 32 + lg * 8];
#pragma unroll
        for (int f = 0; f < 8; ++f) {
            v8bf bfv = *(const v8bf*)(W2T + (f * 16 + lr) * H_DIM + ks * 32 + lg * 8);
            acc2A[f] = __builtin_amdgcn_mfma_f32_16x16x32_bf16(afA2, bfv, acc2A[f], 0, 0, 0);
            acc2B[f] = __builtin_amdgcn_mfma_f32_16x16x32_bf16(afB2, bfv, acc2B[f], 0, 0, 0);
        }
    }

    // ---- epilogue: + b2, encode, fire-and-forget scatter-max ----
#pragma unroll
    for (int g = 0; g < 2; ++g) {
        const int rb = w * 32 + g * 16 + lg * 4;
#pragma unroll
        for (int j = 0; j < 4; ++j) {
            const long ej = e0 + rb + j;
            if (ej < E) {
                const int node = idx_s[rb + j];
                unsigned* dst = agg + (long)node * H_DIM + lr;
#pragma unroll
                for (int f = 0; f < 8; ++f) {
                    float v = (g ? acc2B[f][j] : acc2A[f][j]) + b2_s[f * 16 + lr];
                    atomicMax(dst + f * 16, enc_f32(v));
                }
            }
        }
    }
}

// one wave per node row: lang = center + dec(agg); out = cos(gcn, lang)
__global__ __launch_bounds__(256) void cos_kernel(
    const float* __restrict__ center, const float* __restrict__ gcn,
    const unsigned* __restrict__ agg, float* __restrict__ out, int N)
{
    const int w = threadIdx.x >> 6, l = threadIdx.x & 63;
    const long row = (long)blockIdx.x * 4 + w;
    if (row >= N) return;
    const float2 g2 = *(const float2*)(gcn    + row * H_DIM + l * 2);
    const float2 c2 = *(const float2*)(center + row * H_DIM + l * 2);
    const uint2  e2 = *(const uint2*) (agg    + row * H_DIM + l * 2);
    const float l0 = c2.x + dec_f32(e2.x);
    const float l1 = c2.y + dec_f32(e2.y);
    float sgl = g2.x * l0 + g2.y * l1;
    float sgg = g2.x * g2.x + g2.y * g2.y;
    float sll = l0 * l0 + l1 * l1;
#pragma unroll
    for (int off = 32; off; off >>= 1) {
        sgl += __shfl_xor(sgl, off);
        sgg += __shfl_xor(sgg, off);
        sll += __shfl_xor(sll, off);
    }
    if (l == 0) {
        const float na = fmaxf(sqrtf(sgg), 1e-8f);
        const float nb = fmaxf(sqrtf(sll), 1e-8f);
        out[row] = sgl / (na * nb);
    }
}

extern "C" void kernel_launch(void* const* d_in, const int* in_sizes, int n_in,
                              void* d_out, int out_size, void* d_ws, size_t ws_size,
                              hipStream_t stream) {
    const float* center = (const float*)d_in[0];
    const float* leaf   = (const float*)d_in[1];
    const int*   nidx   = (const int*)  d_in[2];
    const float* gcn    = (const float*)d_in[3];
    const float* W1     = (const float*)d_in[4];
    const float* b1     = (const float*)d_in[5];
    const float* W2     = (const float*)d_in[6];
    const float* b2     = (const float*)d_in[7];

    const int E = in_sizes[2];             // 1,000,000
    const int N = in_sizes[0] / H_DIM;     // 65,536

    unsigned* agg = (unsigned*)d_ws;
    const size_t aggBytes = (size_t)N * H_DIM * sizeof(unsigned);
    __bf16* W1C = (__bf16*)((char*)d_ws + aggBytes);
    __bf16* W2T = W1C + (size_t)F_IN * H_DIM;

    hipMemsetAsync(agg, 0, aggBytes, stream);
    wconvert<<<(F_IN * H_DIM + H_DIM * H_DIM + 255) / 256, 256, 0, stream>>>(W1, W2, W1C, W2T);
    mlp_scatter<<<(E + 127) / 128, 256, 0, stream>>>(leaf, nidx, W1C, W2T, b1, b2, agg, E);
    cos_kernel<<<(N + 3) / 4, 256, 0, stream>>>(center, gcn, agg, (float*)d_out, N);
}

// Round 19
// 594.702 us; speedup vs baseline: 1.2911x; 1.0193x over previous
//
#include <hip/hip_runtime.h>

#define H_DIM 128
#define F_IN  384

typedef __bf16 v8bf __attribute__((ext_vector_type(8)));
typedef float  v4f  __attribute__((ext_vector_type(4)));

// order-preserving float <-> uint encoding for atomicMax
__device__ __forceinline__ unsigned enc_f32(float v) {
    unsigned u = __float_as_uint(v);
    return (u & 0x80000000u) ? ~u : (u | 0x80000000u);
}
__device__ __forceinline__ float dec_f32(unsigned e) {
    if (e == 0u) return 0.0f;  // untouched node -> 0 (matches reference where())
    unsigned u = (e & 0x80000000u) ? (e & 0x7fffffffu) : ~e;
    return __uint_as_float(u);
}

// W1 [F_IN][H] fp32 -> W1T [H][F_IN] bf16 ; W2 [H][H] fp32 -> W2T [H][H] bf16
__global__ __launch_bounds__(256) void wconvert(const float* __restrict__ W1,
                                                const float* __restrict__ W2,
                                                __bf16* __restrict__ W1T,
                                                __bf16* __restrict__ W2T) {
    int i = blockIdx.x * 256 + threadIdx.x;
    if (i < F_IN * H_DIM) {
        int col = i / F_IN, k = i % F_IN;
        W1T[i] = (__bf16)W1[k * H_DIM + col];
    } else if (i < F_IN * H_DIM + H_DIM * H_DIM) {
        int j = i - F_IN * H_DIM;
        int col = j / H_DIM, k = j % H_DIM;
        W2T[j] = (__bf16)W2[k * H_DIM + col];
    }
}

// 128 edges per block, 256 threads (4 waves), B-reuse x2 (r16 core, 596us best).
// hs OVERLAYS wb after the K-loop -> LDS ~35.3KB -> 4 blocks/CU = 16 waves/CU.
// Polish vs r16: hs row stride 136 -> 132 elems (66 dwords = 2 mod 32 banks),
// making layer-2's 16 fragment-row reads map to 16 DISTINCT banks (conflict-
// free) instead of 2-way.
__global__ __launch_bounds__(256, 4) void mlp_scatter(
    const float* __restrict__ leaf, const int* __restrict__ nidx,
    const __bf16* __restrict__ W1T, const __bf16* __restrict__ W2T,
    const float* __restrict__ b1, const float* __restrict__ b2,
    unsigned* __restrict__ agg, int E)
{
    // hs[128][132] bf16 = 33792 B; wb[2][128][40] = 20480 B overlays its head
    __shared__ char smem[33792] __attribute__((aligned(16)));
    __bf16 (*wb)[128][40] = (__bf16 (*)[128][40])smem;   // dies at K-loop end
    __bf16 (*hs)[132]     = (__bf16 (*)[132])smem;       // lives after
    __shared__ int   idx_s[128];
    __shared__ float b1_s[H_DIM], b2_s[H_DIM];

    const int t  = threadIdx.x;
    const int w  = t >> 6;
    const int l  = t & 63;
    const int lr = l & 15;   // row/col within fragment
    const int lg = l >> 4;   // k-group
    const long e0 = (long)blockIdx.x * 128;

    if (t < 128) {
        long e = e0 + t;
        idx_s[t] = nidx[e < E ? e : (E - 1)];
    }
    if (t < H_DIM) { b1_s[t] = b1[t]; b2_s[t] = b2[t]; }

    // stage W1T chunk ks=0 into buffer 0 (each thread: 32B of one column)
    {
        const int col = t >> 1, kh = (t & 1) * 16;
        const v8bf* src = (const v8bf*)(W1T + col * F_IN + kh);
        *(v8bf*)&wb[0][col][kh]     = src[0];
        *(v8bf*)&wb[0][col][kh + 8] = src[1];
    }

    long erA = e0 + w * 32 + lr;        // group A rows
    long erB = e0 + w * 32 + 16 + lr;   // group B rows
    if (erA >= E) erA = E - 1;          // clamp (tail-safe)
    if (erB >= E) erB = E - 1;
    const float* arowA = leaf + erA * (long)F_IN + lg * 8;
    const float* arowB = leaf + erB * (long)F_IN + lg * 8;

    const v4f vzero = {0.f, 0.f, 0.f, 0.f};
    v4f accA[8], accB[8];
#pragma unroll
    for (int f = 0; f < 8; ++f) { accA[f] = vzero; accB[f] = vzero; }

    float4 aA0 = *(const float4*)(arowA);
    float4 aA1 = *(const float4*)(arowA + 4);
    float4 aB0 = *(const float4*)(arowB);
    float4 aB1 = *(const float4*)(arowB + 4);
    __syncthreads();

    // ---- layer 1: h = x @ W1, K=384 in 12 steps of 32 ----
    for (int ks = 0; ks < 12; ++ks) {
        float4 nA0 = aA0, nA1 = aA1, nB0 = aB0, nB1 = aB1;
        if (ks + 1 < 12) {
            nA0 = *(const float4*)(arowA + (ks + 1) * 32);
            nA1 = *(const float4*)(arowA + (ks + 1) * 32 + 4);
            nB0 = *(const float4*)(arowB + (ks + 1) * 32);
            nB1 = *(const float4*)(arowB + (ks + 1) * 32 + 4);
            const int col = t >> 1, kh = (t & 1) * 16;
            const v8bf* src = (const v8bf*)(W1T + col * F_IN + (ks + 1) * 32 + kh);
            const int b = (ks + 1) & 1;
            *(v8bf*)&wb[b][col][kh]     = src[0];
            *(v8bf*)&wb[b][col][kh + 8] = src[1];
        }
        v8bf afA, afB;
        afA[0] = (__bf16)aA0.x; afA[1] = (__bf16)aA0.y; afA[2] = (__bf16)aA0.z; afA[3] = (__bf16)aA0.w;
        afA[4] = (__bf16)aA1.x; afA[5] = (__bf16)aA1.y; afA[6] = (__bf16)aA1.z; afA[7] = (__bf16)aA1.w;
        afB[0] = (__bf16)aB0.x; afB[1] = (__bf16)aB0.y; afB[2] = (__bf16)aB0.z; afB[3] = (__bf16)aB0.w;
        afB[4] = (__bf16)aB1.x; afB[5] = (__bf16)aB1.y; afB[6] = (__bf16)aB1.z; afB[7] = (__bf16)aB1.w;
        const int cb = ks & 1;
#pragma unroll
        for (int f = 0; f < 8; ++f) {
            v8bf bfv = *(const v8bf*)&wb[cb][f * 16 + lr][lg * 8];
            accA[f] = __builtin_amdgcn_mfma_f32_16x16x32_bf16(afA, bfv, accA[f], 0, 0, 0);
            accB[f] = __builtin_amdgcn_mfma_f32_16x16x32_bf16(afB, bfv, accB[f], 0, 0, 0);
        }
        aA0 = nA0; aA1 = nA1; aB0 = nB0; aB1 = nB1;
        __syncthreads();
    }
    // loop's final barrier: all wb reads complete -> hs may overlay wb

    // ---- relu + bias -> bf16 hidden in LDS (wave-private rows) ----
#pragma unroll
    for (int f = 0; f < 8; ++f) {
        const float bb = b1_s[f * 16 + lr];
#pragma unroll
        for (int j = 0; j < 4; ++j) {
            float vA = fmaxf(accA[f][j] + bb, 0.0f);
            float vB = fmaxf(accB[f][j] + bb, 0.0f);
            hs[w * 32 + lg * 4 + j][f * 16 + lr]      = (__bf16)vA;
            hs[w * 32 + 16 + lg * 4 + j][f * 16 + lr] = (__bf16)vB;
        }
    }
    // no barrier: layer 2 reads only this wave's own rows (intra-wave lgkmcnt)

    // ---- layer 2: m = h @ W2, K=128 in 4 steps; W2T frags from L1/L2, reused x2 ----
    v4f acc2A[8], acc2B[8];
#pragma unroll
    for (int f = 0; f < 8; ++f) { acc2A[f] = vzero; acc2B[f] = vzero; }
#pragma unroll
    for (int ks = 0; ks < 4; ++ks) {
        v8bf afA2 = *(const v8bf*)&hs[w * 32 + lr][ks * 32 + lg * 8];
        v8bf afB2 = *(const v8bf*)&hs[w * 32 + 16 + lr][ks * 32 + lg * 8];
#pragma unroll
        for (int f = 0; f < 8; ++f) {
            v8bf bfv = *(const v8bf*)(W2T + (f * 16 + lr) * H_DIM + ks * 32 + lg * 8);
            acc2A[f] = __builtin_amdgcn_mfma_f32_16x16x32_bf16(afA2, bfv, acc2A[f], 0, 0, 0);
            acc2B[f] = __builtin_amdgcn_mfma_f32_16x16x32_bf16(afB2, bfv, acc2B[f], 0, 0, 0);
        }
    }

    // ---- epilogue: + b2, encode, fire-and-forget scatter-max ----
#pragma unroll
    for (int g = 0; g < 2; ++g) {
        const int rb = w * 32 + g * 16 + lg * 4;
#pragma unroll
        for (int j = 0; j < 4; ++j) {
            const long ej = e0 + rb + j;
            if (ej < E) {
                const int node = idx_s[rb + j];
                unsigned* dst = agg + (long)node * H_DIM + lr;
#pragma unroll
                for (int f = 0; f < 8; ++f) {
                    float v = (g ? acc2B[f][j] : acc2A[f][j]) + b2_s[f * 16 + lr];
                    atomicMax(dst + f * 16, enc_f32(v));
                }
            }
        }
    }
}

// one wave per node row: lang = center + dec(agg); out = cos(gcn, lang)
__global__ __launch_bounds__(256) void cos_kernel(
    const float* __restrict__ center, const float* __restrict__ gcn,
    const unsigned* __restrict__ agg, float* __restrict__ out, int N)
{
    const int w = threadIdx.x >> 6, l = threadIdx.x & 63;
    const long row = (long)blockIdx.x * 4 + w;
    if (row >= N) return;
    const float2 g2 = *(const float2*)(gcn    + row * H_DIM + l * 2);
    const float2 c2 = *(const float2*)(center + row * H_DIM + l * 2);
    const uint2  e2 = *(const uint2*) (agg    + row * H_DIM + l * 2);
    const float l0 = c2.x + dec_f32(e2.x);
    const float l1 = c2.y + dec_f32(e2.y);
    float sgl = g2.x * l0 + g2.y * l1;
    float sgg = g2.x * g2.x + g2.y * g2.y;
    float sll = l0 * l0 + l1 * l1;
#pragma unroll
    for (int off = 32; off; off >>= 1) {
        sgl += __shfl_xor(sgl, off);
        sgg += __shfl_xor(sgg, off);
        sll += __shfl_xor(sll, off);
    }
    if (l == 0) {
        const float na = fmaxf(sqrtf(sgg), 1e-8f);
        const float nb = fmaxf(sqrtf(sll), 1e-8f);
        out[row] = sgl / (na * nb);
    }
}

extern "C" void kernel_launch(void* const* d_in, const int* in_sizes, int n_in,
                              void* d_out, int out_size, void* d_ws, size_t ws_size,
                              hipStream_t stream) {
    const float* center = (const float*)d_in[0];
    const float* leaf   = (const float*)d_in[1];
    const int*   nidx   = (const int*)  d_in[2];
    const float* gcn    = (const float*)d_in[3];
    const float* W1     = (const float*)d_in[4];
    const float* b1     = (const float*)d_in[5];
    const float* W2     = (const float*)d_in[6];
    const float* b2     = (const float*)d_in[7];

    const int E = in_sizes[2];             // 1,000,000
    const int N = in_sizes[0] / H_DIM;     // 65,536

    unsigned* agg = (unsigned*)d_ws;
    const size_t aggBytes = (size_t)N * H_DIM * sizeof(unsigned);
    __bf16* W1T = (__bf16*)((char*)d_ws + aggBytes);
    __bf16* W2T = W1T + (size_t)F_IN * H_DIM;

    hipMemsetAsync(agg, 0, aggBytes, stream);
    wconvert<<<(F_IN * H_DIM + H_DIM * H_DIM + 255) / 256, 256, 0, stream>>>(W1, W2, W1T, W2T);
    mlp_scatter<<<(E + 127) / 128, 256, 0, stream>>>(leaf, nidx, W1T, W2T, b1, b2, agg, E);
    cos_kernel<<<(N + 3) / 4, 256, 0, stream>>>(center, gcn, agg, (float*)d_out, N);
}